// Round 9
// baseline (354.683 us; speedup 1.0000x reference)
//
#include <hip/hip_runtime.h>
#include <cstdint>

// ---------------------------------------------------------------------------
// QuantumCoherentLayer collapsed:
//   out[b,h2] = sum_p wHI[p]*coh[b,p,h2] + (x @ Win @ WeffLO)[b,h2]
//   w[j] = (alpha/64)*colsum_j(softmax_rows(cos(phase*J_sym)))
//   wLO = w*(1-alpha) folded into Weff; wHI = w*alpha.
// R9: ONE persistent kernel, 256 blocks x 512 threads (co-residency capacity
// 2 blocks/CU at launch_bounds(512,4) => grid<=capacity => grid barrier is
// deadlock-free). Phases separated by device-scope atomic barriers:
//   P0: wefft frag build + x/Win bf16-frag converts + coh partial -> out
//       (all HBM streams overlapped in one phase)
//   P1: wct frag = wefrag x winfrag (L2+MFMA)
//   P2: out += x @ wct (frag GEMM, RMW onto coh partial)
// Frag order: slot = ((rt*32+kt)*64+lane)*8 shorts; lane=(row%16)+16*((k%32)/8)
// holds k%8..+7 (m89-verified; same for A and B operands).
// ---------------------------------------------------------------------------

typedef __attribute__((ext_vector_type(8))) __bf16 bf16x8;
typedef __attribute__((ext_vector_type(4))) float f32x4;
typedef unsigned short u16;

__device__ __forceinline__ u16 f32_to_bf16_rne(float f) {
  unsigned int u = __float_as_uint(f);
  u += 0x7fffu + ((u >> 16) & 1u);
  return (u16)(u >> 16);
}

__device__ __forceinline__ f32x4 ld4(const float* p) { return *(const f32x4*)p; }

// Per-wave scalars; lane ends with w for j=(lane&7), plus alpha.
__device__ __forceinline__ void wave_scalars(const float* __restrict__ J,
                                             const float* __restrict__ t,
                                             float* w_out, float* alpha_out) {
  const int lane = threadIdx.x & 63;
  float tv = t[0];
  float alpha = fminf(fmaxf(expf(-tv / 51.0f), 0.0f), 1.0f);
  float phase = 2.0f * 3.14159265358979323846f * 20.0f * tv / 1000.0f;
  int i = lane >> 3, j = lane & 7;
  float jsym = 0.5f * (J[i * 8 + j] + J[j * 8 + i]);
  float e = expf(cosf(phase * jsym));
  float rs = e;
  rs += __shfl_xor(rs, 1);
  rs += __shfl_xor(rs, 2);
  rs += __shfl_xor(rs, 4);
  float p = e / rs;
  float cs = p;
  cs += __shfl_xor(cs, 8);
  cs += __shfl_xor(cs, 16);
  cs += __shfl_xor(cs, 32);
  *w_out = alpha * (1.0f / 64.0f) * cs;
  *alpha_out = alpha;
}

// Device-scope grid barrier. Safe because grid(256) <= resident capacity(512).
__device__ __forceinline__ void grid_barrier(unsigned* cnt, unsigned target) {
  __syncthreads();
  __threadfence();  // release: drain + writeback so other XCDs see our stores
  if (threadIdx.x == 0) {
    __hip_atomic_fetch_add(cnt, 1u, __ATOMIC_ACQ_REL, __HIP_MEMORY_SCOPE_AGENT);
    while (__hip_atomic_load(cnt, __ATOMIC_RELAXED, __HIP_MEMORY_SCOPE_AGENT) <
           target)
      __builtin_amdgcn_s_sleep(2);
  }
  __syncthreads();
  __threadfence();  // acquire: invalidate stale lines before reading peers' data
}

__global__ __launch_bounds__(512, 4) void k_fused(
    const float* __restrict__ x, const float* __restrict__ win,
    const float* __restrict__ wp, const float* __restrict__ J,
    const float* __restrict__ t, const float* __restrict__ coh,
    u16* __restrict__ xfrag, u16* __restrict__ winfrag,
    u16* __restrict__ wefrag, u16* __restrict__ wctfrag,
    float* __restrict__ out, unsigned* __restrict__ cnt) {
  __shared__ __align__(16) char smem[33024];
  const int blk = blockIdx.x;   // 256
  const int tid = threadIdx.x;  // 512
  const int wave = tid >> 6, lane = tid & 63;
  const int quad = lane >> 4, t16 = lane & 15;

  float wv, alpha;
  wave_scalars(J, t, &wv, &alpha);
  float wLO[8], wHI[8];
#pragma unroll
  for (int p = 0; p < 8; p++) {
    float wj = __shfl(wv, (lane & 56) | p);
    wLO[p] = wj * (1.0f - alpha);
    wHI[p] = wj * alpha;
  }

  // ---------------- P0a: wefft frag build, two 32(h1)x64(h2) tiles ---------
  {
    float* lt = (float*)smem;  // [2][32][68]
    const int row = tid >> 4, ch = tid & 15;
    f32x4 v[2][8];
#pragma unroll
    for (int u = 0; u < 2; u++) {
      const int tau = 2 * blk + u;
      const int a0 = (tau & 31) * 32, b0 = (tau >> 5) * 64;
      const float* base = wp + (size_t)(a0 + row) * 1024 + b0 + ch * 4;
#pragma unroll
      for (int j = 0; j < 8; j++) v[u][j] = ld4(base + (size_t)j * 1048576);
    }
#pragma unroll
    for (int u = 0; u < 2; u++) {
      f32x4 acc = {0.f, 0.f, 0.f, 0.f};
#pragma unroll
      for (int j = 0; j < 8; j++) acc += wLO[j] * v[u][j];
      *(f32x4*)&lt[(u * 32 + row) * 68 + ch * 4] = acc;
    }
    __syncthreads();
    {
      const int u = tid >> 8, utid = tid & 255;
      const int lf = utid & 63, rtl = utid >> 6;
      const int tau = 2 * blk + u;
      const int a0 = (tau & 31) * 32, b0 = (tau >> 5) * 64;
      const int rowh2 = rtl * 16 + (lf & 15);
      const int kh1 = (lf >> 4) << 3;
      __align__(16) u16 o[8];
#pragma unroll
      for (int i = 0; i < 8; i++)
        o[i] = f32_to_bf16_rne(lt[(u * 32 + kh1 + i) * 68 + rowh2]);
      *(uint4*)(wefrag +
                ((size_t)(((b0 >> 4) + rtl) * 32 + (a0 >> 5)) * 64 + lf) * 8) =
          *(const uint4*)o;
    }
    __syncthreads();
  }

  // ---------------- P0b: converts (blocks 0..191), 16 rows each ------------
  if (blk < 192) {
    const float* src;
    u16* dst;
    if (blk < 128) {
      src = x + (size_t)blk * 16384;
      dst = xfrag + (size_t)blk * 16384;
    } else {
      src = win + (size_t)(blk - 128) * 16384;
      dst = winfrag + (size_t)(blk - 128) * 16384;
    }
    u16* ld = (u16*)smem;  // [16][1032]
    f32x4 v[8];
#pragma unroll
    for (int s = 0; s < 8; s++) {
      int u2 = s * 512 + tid;
      v[s] = ld4(src + (u2 >> 8) * 1024 + (u2 & 255) * 4);
    }
#pragma unroll
    for (int s = 0; s < 8; s++) {
      int u2 = s * 512 + tid;
      ushort4 o;
      o.x = f32_to_bf16_rne(v[s][0]);
      o.y = f32_to_bf16_rne(v[s][1]);
      o.z = f32_to_bf16_rne(v[s][2]);
      o.w = f32_to_bf16_rne(v[s][3]);
      *(ushort4*)(ld + (u2 >> 8) * 1032 + (u2 & 255) * 4) = o;
    }
    __syncthreads();
#pragma unroll
    for (int s = 0; s < 4; s++) {
      int idx = s * 512 + tid;
      int lf = idx & 63, kt = idx >> 6;
      int row = lf & 15, colb = kt * 32 + ((lf >> 4) << 3);
      *(uint4*)(dst + (kt * 64 + lf) * 8) = *(const uint4*)(ld + row * 1032 + colb);
    }
  }

  // ---------------- P0c: coh partial -> out (this block's two P2 tiles) ----
#pragma unroll
  for (int half = 0; half < 2; half++) {
    f32x4 v[2][8];
    float* outp[2];
#pragma unroll
    for (int c = 0; c < 2; c++) {
      const int cc = half * 2 + c;
      const int u = cc >> 1, q = cc & 1;
      const int tau = 2 * blk + u;
      const int m0 = (tau >> 4) * 64, n0 = (tau & 15) * 64;
      const int unit = q * 512 + tid;
      const int row = unit >> 4, ch = unit & 15;
      const float* cb = coh + (size_t)(m0 + row) * 8192 + n0 + ch * 4;
#pragma unroll
      for (int p = 0; p < 8; p++) v[c][p] = ld4(cb + p * 1024);
      outp[c] = out + (size_t)(m0 + row) * 1024 + n0 + ch * 4;
    }
#pragma unroll
    for (int c = 0; c < 2; c++) {
      f32x4 a = {0.f, 0.f, 0.f, 0.f};
#pragma unroll
      for (int p = 0; p < 8; p++) a += wHI[p] * v[c][p];
      *(f32x4*)outp[c] = a;
    }
  }

  grid_barrier(cnt, 256);

  // ---------------- P1: wct frag = wefrag x winfrag ------------------------
  {
    const int m0 = (blk & 15) * 64;                      // h2
    const int n0 = (blk >> 4) * 64 + (wave >> 2) * 32;   // d
    const int uw = wave & 3;
    const u16* ap = wefrag + ((size_t)((m0 + uw * 16) >> 4) * 32) * 512 + lane * 8;
    const u16* bp = winfrag + ((size_t)(n0 >> 4) * 32) * 512 + lane * 8;
    f32x4 acc[2] = {{0.f, 0.f, 0.f, 0.f}, {0.f, 0.f, 0.f, 0.f}};
    for (int kb = 0; kb < 32; kb += 4) {
      bf16x8 a[4], b0[4], b1[4];
#pragma unroll
      for (int u = 0; u < 4; u++) {
        a[u] = *(const bf16x8*)(ap + (kb + u) * 512);
        b0[u] = *(const bf16x8*)(bp + (kb + u) * 512);
        b1[u] = *(const bf16x8*)(bp + (32 + kb + u) * 512);
      }
#pragma unroll
      for (int u = 0; u < 4; u++) {
        acc[0] = __builtin_amdgcn_mfma_f32_16x16x32_bf16(a[u], b0[u], acc[0], 0, 0, 0);
        acc[1] = __builtin_amdgcn_mfma_f32_16x16x32_bf16(a[u], b1[u], acc[1], 0, 0, 0);
      }
    }
    u16* ct = (u16*)smem;  // [2][64][36]
    u16* ctu = ct + (wave >> 2) * 64 * 36;
#pragma unroll
    for (int r = 0; r < 4; r++)
#pragma unroll
      for (int ni = 0; ni < 2; ni++)
        ctu[(uw * 16 + quad * 4 + r) * 36 + ni * 16 + t16] =
            f32_to_bf16_rne(acc[ni][r]);
    __syncthreads();
    {
      const int ug = tid >> 8, utid = tid & 255;
      const int n0u = (blk >> 4) * 64 + ug * 32;
      const int lf = utid & 63, rtl = utid >> 6;
      const int rowl = rtl * 16 + (lf & 15), colb = (lf >> 4) << 3;
      const u16* ctg = ct + ug * 64 * 36;
      __align__(16) u16 o[8];
#pragma unroll
      for (int i = 0; i < 8; i++) o[i] = ctg[rowl * 36 + colb + i];
      *(uint4*)(wctfrag +
                ((size_t)(((m0 >> 4) + rtl) * 32 + (n0u >> 5)) * 64 + lf) * 8) =
          *(const uint4*)o;
    }
  }

  grid_barrier(cnt, 512);

  // ---------------- P2: out += x @ wct (RMW onto coh partial) --------------
  {
    const int wm = (wave >> 2) * 32, wn = (wave & 3) * 16;
#pragma unroll
    for (int u = 0; u < 2; u++) {
      const int tau = 2 * blk + u;
      const int m0 = (tau >> 4) * 64, n0 = (tau & 15) * 64;
      const u16* ap = xfrag + ((size_t)((m0 + wm) >> 4) * 32) * 512 + lane * 8;
      const u16* bp = wctfrag + ((size_t)((n0 + wn) >> 4) * 32) * 512 + lane * 8;
      float cpre[2][4];
#pragma unroll
      for (int mi = 0; mi < 2; mi++)
#pragma unroll
        for (int r = 0; r < 4; r++)
          cpre[mi][r] =
              out[(size_t)(m0 + wm + mi * 16 + quad * 4 + r) * 1024 + n0 + wn + t16];
      f32x4 acc[2] = {{0.f, 0.f, 0.f, 0.f}, {0.f, 0.f, 0.f, 0.f}};
      for (int kb = 0; kb < 32; kb += 4) {
        bf16x8 a0[4], a1[4], b[4];
#pragma unroll
        for (int uu = 0; uu < 4; uu++) {
          a0[uu] = *(const bf16x8*)(ap + (kb + uu) * 512);
          a1[uu] = *(const bf16x8*)(ap + (32 + kb + uu) * 512);
          b[uu] = *(const bf16x8*)(bp + (kb + uu) * 512);
        }
#pragma unroll
        for (int uu = 0; uu < 4; uu++) {
          acc[0] = __builtin_amdgcn_mfma_f32_16x16x32_bf16(a0[uu], b[uu], acc[0], 0, 0, 0);
          acc[1] = __builtin_amdgcn_mfma_f32_16x16x32_bf16(a1[uu], b[uu], acc[1], 0, 0, 0);
        }
      }
#pragma unroll
      for (int mi = 0; mi < 2; mi++)
#pragma unroll
        for (int r = 0; r < 4; r++)
          out[(size_t)(m0 + wm + mi * 16 + quad * 4 + r) * 1024 + n0 + wn + t16] =
              acc[mi][r] + cpre[mi][r];
    }
  }
}

// ---------------------------------------------------------------------------
extern "C" void kernel_launch(void* const* d_in, const int* in_sizes, int n_in,
                              void* d_out, int out_size, void* d_ws, size_t ws_size,
                              hipStream_t stream) {
  const float* x   = (const float*)d_in[0];  // [2048,1024]
  const float* win = (const float*)d_in[1];  // [1024,1024]
  const float* wp  = (const float*)d_in[2];  // [8,1024,1024]
  const float* J   = (const float*)d_in[3];  // [8,8]
  const float* coh = (const float*)d_in[4];  // [2048,8,1024]
  const float* t   = (const float*)d_in[5];  // [1]
  float* out = (float*)d_out;                // [2048,1024] fp32

  char* ws = (char*)d_ws;
  u16* xfrag   = (u16*)ws;                          // 4 MB, rt=b/16,  kt=d/32
  u16* winfrag = (u16*)(ws + 4u * 1024 * 1024);     // 2 MB, rt=d/16,  kt=h1/32
  u16* wefrag  = (u16*)(ws + 6u * 1024 * 1024);     // 2 MB, rt=h2/16, kt=h1/32
  u16* wctfrag = (u16*)(ws + 8u * 1024 * 1024);     // 2 MB, rt=h2/16, kt=d/32
  unsigned* cnt = (unsigned*)(ws + 12u * 1024 * 1024);

  hipMemsetAsync(cnt, 0, 64, stream);  // barrier counter (ws is 0xAA-poisoned)
  k_fused<<<256, 512, 0, stream>>>(x, win, wp, J, t, coh, xfrag, winfrag,
                                   wefrag, wctfrag, out, cnt);
}

// Round 10
// 158.801 us; speedup vs baseline: 2.2335x; 2.2335x over previous
//
#include <hip/hip_runtime.h>
#include <cstdint>

// ---------------------------------------------------------------------------
// QuantumCoherentLayer collapsed:
//   out[b,h2] = sum_p wHI[p]*coh[b,p,h2] + (x @ Win @ WeffLO)[b,h2]
//   w[j] = (alpha/64)*colsum_j(softmax_rows(cos(phase*J_sym)))
//   wLO = w*(1-alpha) folded into Weff; wHI = w*alpha.
// Frag order: slot = ((rt*32+kt)*64+lane)*8 shorts; lane=(row%16)+16*((k%32)/8)
// holds k%8..+7 (m89-verified; same for A and B operands).
// R10 (harness overhead measured at ~99 us via R9; kernel budget ~58 -> ~30):
//   k_prep : ALL input streams: wefft frag build + x convert + win convert
//   k_gemm0: wct frag = wefrag x winfrag (tiny, L2+MFMA)
//   k_main : phase1 all-512-thread coh stream -> LDS reduce (16x16B
//            outstanding/thread, full HBM MLP); phase2 all-8-wave frag GEMM
//            accumulating into the same LDS tile; coalesced f32x4 out writes.
// ---------------------------------------------------------------------------

typedef __attribute__((ext_vector_type(8))) __bf16 bf16x8;
typedef __attribute__((ext_vector_type(4))) float f32x4;
typedef unsigned short u16;

__device__ __forceinline__ u16 f32_to_bf16_rne(float f) {
  unsigned int u = __float_as_uint(f);
  u += 0x7fffu + ((u >> 16) & 1u);
  return (u16)(u >> 16);
}

__device__ __forceinline__ f32x4 nt4(const float* p) {
  return __builtin_nontemporal_load((const f32x4*)p);
}

// Per-wave scalars; lane ends with w for j=(lane&7), plus alpha.
__device__ __forceinline__ void wave_scalars(const float* __restrict__ J,
                                             const float* __restrict__ t,
                                             float* w_out, float* alpha_out) {
  const int lane = threadIdx.x & 63;
  float tv = t[0];
  float alpha = fminf(fmaxf(expf(-tv / 51.0f), 0.0f), 1.0f);
  float phase = 2.0f * 3.14159265358979323846f * 20.0f * tv / 1000.0f;
  int i = lane >> 3, j = lane & 7;
  float jsym = 0.5f * (J[i * 8 + j] + J[j * 8 + i]);
  float e = expf(cosf(phase * jsym));
  float rs = e;
  rs += __shfl_xor(rs, 1);
  rs += __shfl_xor(rs, 2);
  rs += __shfl_xor(rs, 4);
  float p = e / rs;
  float cs = p;
  cs += __shfl_xor(cs, 8);
  cs += __shfl_xor(cs, 16);
  cs += __shfl_xor(cs, 32);
  *w_out = alpha * (1.0f / 64.0f) * cs;
  *alpha_out = alpha;
}

// fp32 [16 rows x 1024] -> bf16 frag via LDS tile (256 threads)
__device__ __forceinline__ void convert16(const float* __restrict__ src,
                                          u16* __restrict__ dst, u16* ld,
                                          int tid) {
  f32x4 v[16];
#pragma unroll
  for (int row = 0; row < 16; row++) v[row] = nt4(src + row * 1024 + tid * 4);
#pragma unroll
  for (int row = 0; row < 16; row++) {
    ushort4 o;
    o.x = f32_to_bf16_rne(v[row][0]);
    o.y = f32_to_bf16_rne(v[row][1]);
    o.z = f32_to_bf16_rne(v[row][2]);
    o.w = f32_to_bf16_rne(v[row][3]);
    *(ushort4*)(ld + row * 1032 + tid * 4) = o;
  }
  __syncthreads();
#pragma unroll
  for (int s = 0; s < 8; s++) {
    int idx = s * 256 + tid;
    int lf = idx & 63, kt = idx >> 6;
    int row = lf & 15, colb = kt * 32 + ((lf >> 4) << 3);
    *(uint4*)(dst + (kt * 64 + lf) * 8) = *(const uint4*)(ld + row * 1032 + colb);
  }
}

// ---------------------------------------------------------------------------
// k_prep, 704 blocks x 256:
//  [0,512)   : wefft 32(h1) x 64(h2) tile -> frag order (rows h2, k h1)
//  [512,640) : x fp32 -> bf16 frag
//  [640,704) : Win fp32 -> bf16 frag
// ---------------------------------------------------------------------------
__global__ __launch_bounds__(256, 4) void k_prep(
    const float* __restrict__ x, const float* __restrict__ win,
    const float* __restrict__ wp, const float* __restrict__ J,
    const float* __restrict__ t, u16* __restrict__ xfrag,
    u16* __restrict__ winfrag, u16* __restrict__ wefrag) {
  __shared__ __align__(16) char smem[33024];
  const int blk = blockIdx.x;
  const int tid = threadIdx.x;
  const int lane = tid & 63;

  if (blk < 512) {
    float* lt = (float*)smem;  // [32][68]  lt[h1l][h2l]
    float wv, alpha;
    wave_scalars(J, t, &wv, &alpha);
    float wLO[8];
#pragma unroll
    for (int p = 0; p < 8; p++)
      wLO[p] = __shfl(wv, (lane & 56) | p) * (1.0f - alpha);
    const int a0 = (blk & 31) * 32;  // h1 base
    const int b0 = (blk >> 5) * 64;  // h2 base
    f32x4 v[2][8];
#pragma unroll
    for (int s = 0; s < 2; s++) {
      const int item = s * 256 + tid;
      const int row = item >> 4, ch = item & 15;
      const float* base = wp + (size_t)(a0 + row) * 1024 + b0 + ch * 4;
#pragma unroll
      for (int j = 0; j < 8; j++) v[s][j] = nt4(base + (size_t)j * 1048576);
    }
#pragma unroll
    for (int s = 0; s < 2; s++) {
      const int item = s * 256 + tid;
      const int row = item >> 4, ch = item & 15;
      f32x4 acc = {0.f, 0.f, 0.f, 0.f};
#pragma unroll
      for (int j = 0; j < 8; j++) acc += wLO[j] * v[s][j];
      *(f32x4*)&lt[row * 68 + ch * 4] = acc;
    }
    __syncthreads();
    {
      const int lf = tid & 63, rtl = tid >> 6;
      const int rowh2 = rtl * 16 + (lf & 15);
      const int kh1 = (lf >> 4) << 3;
      __align__(16) u16 o[8];
#pragma unroll
      for (int i = 0; i < 8; i++)
        o[i] = f32_to_bf16_rne(lt[(kh1 + i) * 68 + rowh2]);
      const int rt = (b0 >> 4) + rtl, kt = a0 >> 5;
      *(uint4*)(wefrag + ((size_t)(rt * 32 + kt) * 64 + lf) * 8) = *(const uint4*)o;
    }
  } else if (blk < 640) {
    const int cid = blk - 512;  // 128 blocks of x
    convert16(x + (size_t)cid * 16384, xfrag + (size_t)cid * 16384, (u16*)smem,
              tid);
  } else {
    const int cid = blk - 640;  // 64 blocks of win
    convert16(win + (size_t)cid * 16384, winfrag + (size_t)cid * 16384,
              (u16*)smem, tid);
  }
}

// ---------------------------------------------------------------------------
// k_gemm0, 512 blocks x 256: wct frag = wefrag(h2) x winfrag(d), K=1024.
// Tiles 64(h2) x 32(d), XCD-swizzled. Epilogue -> B-frag order for k_main.
// ---------------------------------------------------------------------------
__global__ __launch_bounds__(256, 4) void k_gemm0(const u16* __restrict__ Af,
                                                  const u16* __restrict__ Bf,
                                                  u16* __restrict__ ofrag) {
  __shared__ u16 ct[64 * 36];
  const int tid = threadIdx.x;
  const int wave = tid >> 6, lane = tid & 63;
  const int quad = lane >> 4, t16 = lane & 15;
  const int xcd = blockIdx.x & 7, i = blockIdx.x >> 3;
  const int m0 = (xcd + 8 * (i & 1)) * 64;  // h2
  const int n0 = (i >> 1) * 32;             // d
  const u16* ap = Af + ((size_t)((m0 + wave * 16) >> 4) * 32) * 512 + lane * 8;
  const u16* bp = Bf + ((size_t)(n0 >> 4) * 32) * 512 + lane * 8;

  f32x4 acc[2] = {{0.f, 0.f, 0.f, 0.f}, {0.f, 0.f, 0.f, 0.f}};
  for (int kb = 0; kb < 32; kb += 4) {
    bf16x8 a[4], b0[4], b1[4];
#pragma unroll
    for (int u = 0; u < 4; u++) {
      a[u] = *(const bf16x8*)(ap + (kb + u) * 512);
      b0[u] = *(const bf16x8*)(bp + (kb + u) * 512);
      b1[u] = *(const bf16x8*)(bp + (32 + kb + u) * 512);
    }
#pragma unroll
    for (int u = 0; u < 4; u++) {
      acc[0] = __builtin_amdgcn_mfma_f32_16x16x32_bf16(a[u], b0[u], acc[0], 0, 0, 0);
      acc[1] = __builtin_amdgcn_mfma_f32_16x16x32_bf16(a[u], b1[u], acc[1], 0, 0, 0);
    }
  }
#pragma unroll
  for (int r = 0; r < 4; r++)
#pragma unroll
    for (int ni = 0; ni < 2; ni++)
      ct[(wave * 16 + quad * 4 + r) * 36 + ni * 16 + t16] =
          f32_to_bf16_rne(acc[ni][r]);
  __syncthreads();
  {
    int lf = tid & 63, rtl = tid >> 6;
    int rowl = rtl * 16 + (lf & 15);
    int colb = (lf >> 4) << 3;
    __align__(16) u16 o[8];
#pragma unroll
    for (int i2 = 0; i2 < 8; i2++) o[i2] = ct[rowl * 36 + colb + i2];
    *(uint4*)(ofrag +
              ((size_t)(((m0 >> 4) + rtl) * 32 + (n0 >> 5)) * 64 + lf) * 8) =
        *(const uint4*)o;
  }
}

// ---------------------------------------------------------------------------
// k_main, 512 blocks x 512 thr, XCD-swizzled. Tile 64(b) x 64(h2).
// Phase 1: all threads stream coh slice (each: 2 (row,chunk) pairs x 8 p =
//          16 nt f32x4 loads outstanding), weighted-reduce into LDS.
// Phase 2: all 8 waves frag-GEMM (wave tile 32m x 16n), accumulate into LDS.
// Phase 3: coalesced f32x4 writes of out rows.
// ---------------------------------------------------------------------------
__global__ __launch_bounds__(512, 4) void k_main(
    const u16* __restrict__ Af, const u16* __restrict__ Bf,
    const float* __restrict__ coh, const float* __restrict__ J,
    const float* __restrict__ t, float* __restrict__ out) {
  __shared__ float cs[64 * 68];
  const int tid = threadIdx.x;
  const int wave = tid >> 6, lane = tid & 63;
  const int quad = lane >> 4, t16 = lane & 15;
  const int xcd = blockIdx.x & 7, i = blockIdx.x >> 3;
  const int m0 = (xcd + 8 * (i >> 4)) * 64;  // b tile
  const int n0 = (i & 15) * 64;              // h2 tile

  float wv, alpha;
  wave_scalars(J, t, &wv, &alpha);
  float wHI[8];
#pragma unroll
  for (int p = 0; p < 8; p++) wHI[p] = __shfl(wv, (lane & 56) | p) * alpha;

  // ---- phase 1: coh stream. 1024 (row,chunk) pairs; 2 per thread. ----
  {
    f32x4 v[2][8];
#pragma unroll
    for (int c = 0; c < 2; c++) {
      const int pair = c * 512 + tid;
      const int row = pair >> 4, ch = pair & 15;
      const float* cb = coh + (size_t)(m0 + row) * 8192 + n0 + ch * 4;
#pragma unroll
      for (int p = 0; p < 8; p++) v[c][p] = nt4(cb + p * 1024);
    }
#pragma unroll
    for (int c = 0; c < 2; c++) {
      const int pair = c * 512 + tid;
      const int row = pair >> 4, ch = pair & 15;
      f32x4 a = {0.f, 0.f, 0.f, 0.f};
#pragma unroll
      for (int p = 0; p < 8; p++) a += wHI[p] * v[c][p];
      *(f32x4*)&cs[row * 68 + ch * 4] = a;
    }
  }
  __syncthreads();

  // ---- phase 2: frag GEMM, wave tile 32m x 16n ----
  {
    const int wm = (wave >> 2) * 32, wn = (wave & 3) * 16;
    const u16* ap = Af + ((size_t)((m0 + wm) >> 4) * 32) * 512 + lane * 8;
    const u16* bp = Bf + ((size_t)((n0 + wn) >> 4) * 32) * 512 + lane * 8;
    f32x4 acc[2] = {{0.f, 0.f, 0.f, 0.f}, {0.f, 0.f, 0.f, 0.f}};
    for (int kb = 0; kb < 32; kb += 4) {
      bf16x8 a0[4], a1[4], b[4];
#pragma unroll
      for (int u = 0; u < 4; u++) {
        a0[u] = *(const bf16x8*)(ap + (kb + u) * 512);
        a1[u] = *(const bf16x8*)(ap + (32 + kb + u) * 512);
        b[u] = *(const bf16x8*)(bp + (kb + u) * 512);
      }
#pragma unroll
      for (int u = 0; u < 4; u++) {
        acc[0] = __builtin_amdgcn_mfma_f32_16x16x32_bf16(a0[u], b[u], acc[0], 0, 0, 0);
        acc[1] = __builtin_amdgcn_mfma_f32_16x16x32_bf16(a1[u], b[u], acc[1], 0, 0, 0);
      }
    }
    __syncthreads();  // ensure all phase-1 partials are in LDS (already true)
#pragma unroll
    for (int mi = 0; mi < 2; mi++)
#pragma unroll
      for (int r = 0; r < 4; r++)
        cs[(wm + mi * 16 + quad * 4 + r) * 68 + wn + t16] += acc[mi][r];
  }
  __syncthreads();

  // ---- phase 3: coalesced out writes ----
#pragma unroll
  for (int c = 0; c < 2; c++) {
    const int pair = c * 512 + tid;
    const int row = pair >> 4, ch = pair & 15;
    *(f32x4*)(out + (size_t)(m0 + row) * 1024 + n0 + ch * 4) =
        *(const f32x4*)&cs[row * 68 + ch * 4];
  }
}

// ---------------------------------------------------------------------------
extern "C" void kernel_launch(void* const* d_in, const int* in_sizes, int n_in,
                              void* d_out, int out_size, void* d_ws, size_t ws_size,
                              hipStream_t stream) {
  const float* x   = (const float*)d_in[0];  // [2048,1024]
  const float* win = (const float*)d_in[1];  // [1024,1024]
  const float* wp  = (const float*)d_in[2];  // [8,1024,1024]
  const float* J   = (const float*)d_in[3];  // [8,8]
  const float* coh = (const float*)d_in[4];  // [2048,8,1024]
  const float* t   = (const float*)d_in[5];  // [1]
  float* out = (float*)d_out;                // [2048,1024] fp32

  char* ws = (char*)d_ws;
  u16* xfrag   = (u16*)ws;                         // 4 MB, rt=b/16,  kt=d/32
  u16* winfrag = (u16*)(ws + 4u * 1024 * 1024);    // 2 MB, rt=d/16,  kt=h1/32
  u16* wefrag  = (u16*)(ws + 6u * 1024 * 1024);    // 2 MB, rt=h2/16, kt=h1/32
  u16* wctfrag = (u16*)(ws + 8u * 1024 * 1024);    // 2 MB, rt=h2/16, kt=d/32

  // all input streams: wefft build + x convert + win convert
  k_prep<<<704, 256, 0, stream>>>(x, win, wp, J, t, xfrag, winfrag, wefrag);
  // wct[h2][d] = sum_h1 weff[h2][h1]*win[d][h1]
  k_gemm0<<<512, 256, 0, stream>>>(wefrag, winfrag, wctfrag);
  // out[b][h2] = sum_d x[b][d]*wct[h2][d] + sum_p wHI[p]*coh[b][p][h2]
  k_main<<<512, 512, 0, stream>>>(xfrag, wctfrag, coh, J, t, out);
}